// Round 4
// baseline (556.898 us; speedup 1.0000x reference)
//
#include <hip/hip_runtime.h>

#define NN 50000
#define EE 500000
#define GG 512

typedef _Float16 f16x8 __attribute__((ext_vector_type(8)));
typedef _Float16 f16x2 __attribute__((ext_vector_type(2)));
typedef float f32x16 __attribute__((ext_vector_type(16)));

union F16x8U { f16x8 v8; f16x2 v2[4]; unsigned u[4]; };

__device__ __forceinline__ unsigned splat_h(float a){
  return __builtin_bit_cast(unsigned, __builtin_amdgcn_cvt_pkrtz(a, a));
}

// ---------------------------------------------------------------------------
// Prep: f16 tables (weights + x).
// ---------------------------------------------------------------------------
__launch_bounds__(256)
__global__ void prep_k(const float* __restrict__ x,
                       const float* __restrict__ w2a, const float* __restrict__ b2a,
                       const float* __restrict__ w2b, const float* __restrict__ b2b,
                       _Float16* __restrict__ xh, _Float16* __restrict__ Bt1,
                       _Float16* __restrict__ Bt2)
{
  int idx = blockIdx.x*256 + threadIdx.x;
  if (idx < 32*288){
    int o = idx / 288, ki = idx % 288;
    int k = ki >> 3, i = ki & 7;
    float v = 0.f;
    if (i < 6){
      if (k < 32)       v = w2a[k*192 + i*32 + o];
      else if (k == 32) v = b2a[i*32 + o];
    }
    Bt1[idx] = (_Float16)v;
  } else if (idx < 32*288 + 32*1088){
    int j = idx - 32*288;
    int o = j / 1088, ki = j % 1088;
    int k = ki >> 5, i = ki & 31;
    float v = 0.f;
    if (k < 32)       v = w2b[k*1024 + i*32 + o];
    else if (k == 32) v = b2b[i*32 + o];
    Bt2[j] = (_Float16)v;
  } else {
    int j = idx - (32*288 + 32*1088);
    if (j < NN*8){
      int n = j >> 3, i = j & 7;
      xh[j] = (_Float16)((i < 6) ? x[n*6 + i] : 0.f);
    }
  }
}

// ---------------------------------------------------------------------------
// Counting sort by dst: histogram -> 2-level exclusive scan -> scatter.
// ---------------------------------------------------------------------------
__launch_bounds__(256)
__global__ void hist_k(const int* __restrict__ ei, int* __restrict__ hist)
{
  int e = blockIdx.x*256 + threadIdx.x;
  if (e < EE) atomicAdd(&hist[ei[EE + e]], 1);
}

__launch_bounds__(256)
__global__ void scan1_k(const int* __restrict__ hist, int* __restrict__ part,
                        int* __restrict__ blk)
{
  __shared__ int s[256];
  int t = threadIdx.x, b = blockIdx.x, i = b*256 + t;
  int v = (i < NN) ? hist[i] : 0;
  s[t] = v; __syncthreads();
  #pragma unroll
  for (int off = 1; off < 256; off <<= 1){
    int u = (t >= off) ? s[t-off] : 0;
    __syncthreads();
    s[t] += u;
    __syncthreads();
  }
  if (i < NN) part[i] = s[t] - v;          // exclusive within block
  if (t == 255) blk[b] = s[255];           // block total
}

__launch_bounds__(256)
__global__ void scan2_k(int* __restrict__ blk, int nblk)
{
  __shared__ int s[256];
  int t = threadIdx.x;
  int v = (t < nblk) ? blk[t] : 0;
  s[t] = v; __syncthreads();
  #pragma unroll
  for (int off = 1; off < 256; off <<= 1){
    int u = (t >= off) ? s[t-off] : 0;
    __syncthreads();
    s[t] += u;
    __syncthreads();
  }
  if (t < nblk) blk[t] = s[t] - v;         // exclusive across blocks
}

__launch_bounds__(256)
__global__ void scatter_k(const int* __restrict__ ei, const float* __restrict__ ea,
                          const int* __restrict__ part, const int* __restrict__ blk,
                          int* __restrict__ cursor,
                          int* __restrict__ esrc, int* __restrict__ edst,
                          float* __restrict__ eap)
{
  int e = blockIdx.x*256 + threadIdx.x;
  if (e < EE){
    int d = ei[EE + e];
    int slot = part[d] + blk[d >> 8] + atomicAdd(&cursor[d], 1);
    esrc[slot] = ei[e];
    edst[slot] = d;
    #pragma unroll
    for (int q = 0; q < 5; ++q) eap[(long)slot*5 + q] = ea[(long)e*5 + q];
  }
}

// ---------------------------------------------------------------------------
// NNConv messages on dst-sorted edges: block = 128 edges (4 waves x 32),
// mfma 32x32x16 f16.  z[e][ki] = h'[e][k] * x'[e][i]; msg = z @ Bt;
// scatter atomicAdd to agg[dst] (dst clustered per block -> L2-local).
// D: col = lane&31, row = (reg&3) + 8*(reg>>2) + 4*(lane>>5).
// ---------------------------------------------------------------------------
template<int CONV>
__launch_bounds__(256, 8)
__global__ void conv_msg_k(const _Float16* __restrict__ xh,
                           const int* __restrict__ esrc,
                           const int* __restrict__ edst,
                           const float* __restrict__ eap,
                           const float* __restrict__ w1,
                           const float* __restrict__ b1,
                           const _Float16* __restrict__ Btg,
                           float* __restrict__ agg)
{
  constexpr int KP = (CONV == 1) ? 288 : 1088;
  constexpr int NT = KP / 16;
  __shared__ unsigned hs2[128][37];       // splatted half2 of h', kk = 0..35

  const int tid = threadIdx.x;
  const int e0  = blockIdx.x * 128;

  // cooperative h' = relu(eap@w1 + b1), stored as splatted half2
  {
    int e  = tid >> 1;                    // 0..127
    int kb = (tid & 1) * 16;
    int eg = e0 + e;
    bool valid = eg < EE;
    float eav[5];
    #pragma unroll
    for (int q = 0; q < 5; ++q) eav[q] = valid ? eap[(long)eg*5 + q] : 0.f;
    #pragma unroll
    for (int k = kb; k < kb + 16; ++k){
      float a = b1[k];
      #pragma unroll
      for (int q = 0; q < 5; ++q) a += eav[q] * w1[q*32 + k];
      hs2[e][k] = splat_h(fmaxf(a, 0.f));
    }
    if (kb == 16){
      hs2[e][32] = splat_h(1.f);          // bias row (h' = 1)
      hs2[e][33] = 0u; hs2[e][34] = 0u; hs2[e][35] = 0u;
    }
  }
  __syncthreads();

  const int lane = tid & 63;
  const int wave = tid >> 6;
  const int col  = lane & 31;             // A-row (edge) AND B-col (output)
  const int hi   = lane >> 5;
  const int el   = wave*32 + col;         // block-local edge for A
  const int emy  = e0 + el;
  const int src  = (emy < EE) ? esrc[emy] : 0;

  // x fragments (f16 pairs), register-resident
  F16x8U xa, xb;
  if (CONV == 1){
    xa.v8 = *(const f16x8*)(xh + (long)src*8);
    xb.v8 = xa.v8;
  } else {
    xa.v8 = *(const f16x8*)(xh + (long)src*32 + 8*hi);
    xb.v8 = *(const f16x8*)(xh + (long)src*32 + 16 + 8*hi);
  }

  // h' splats, register-resident (static indexing under full unroll)
  unsigned h2[(CONV == 1) ? 18 : 34];
  if (CONV == 1){
    #pragma unroll
    for (int t = 0; t < 18; ++t) h2[t] = hs2[el][2*t + hi];
  } else {
    #pragma unroll
    for (int kk = 0; kk < 34; ++kk) h2[kk] = hs2[el][kk];
  }

  f32x16 acc;
  #pragma unroll
  for (int r = 0; r < 16; ++r) acc[r] = 0.f;

  const _Float16* bp = Btg + (long)col*KP + 8*hi;
  #pragma unroll
  for (int t = 0; t < NT; ++t){
    f16x8 bf = *(const f16x8*)(bp + 16*t);
    f16x2 hv = __builtin_bit_cast(f16x2, h2[(CONV == 1) ? t : (t >> 1)]);
    const F16x8U& xs = (CONV == 1) ? xa : ((t & 1) ? xb : xa);
    F16x8U af;
    #pragma unroll
    for (int p = 0; p < 4; ++p) af.v2[p] = hv * xs.v2[p];
    acc = __builtin_amdgcn_mfma_f32_32x32x16_f16(af.v8, bf, acc, 0, 0, 0);
  }

  // scatter epilogue (dst sorted -> few distinct lines per block)
  #pragma unroll
  for (int g = 0; g < 4; ++g){
    #pragma unroll
    for (int r = 0; r < 4; ++r){
      int row = r + 8*g + 4*hi;
      int eg  = e0 + wave*32 + row;
      if (eg < EE){
        int d = edst[eg];
        atomicAdd(&agg[(long)d*32 + col], acc[4*g + r]);
      }
    }
  }
}

// ---------------------------------------------------------------------------
// h = agg/max(cnt,1) + x@root + bias (in place), accumulate BN stats.
// ---------------------------------------------------------------------------
template<int IN_C>
__launch_bounds__(256)
__global__ void node_update_k(const float* __restrict__ xin, const float* __restrict__ root,
                              const float* __restrict__ bias, const int* __restrict__ cnt,
                              float* __restrict__ buf, float* __restrict__ stats, int N)
{
  __shared__ float rs[IN_C*32];
  __shared__ float bs[32];
  __shared__ float redS[4][32], redQ[4][32];
  int tid = threadIdx.x;
  for (int i = tid; i < IN_C*32; i += 256) rs[i] = root[i];
  if (tid < 32) bs[tid] = bias[tid];
  __syncthreads();
  int o = tid & 31, slot = tid >> 5;
  float s = 0.f, q = 0.f;
  for (int n = blockIdx.x*8 + slot; n < N; n += gridDim.x*8){
    float c = fmaxf((float)cnt[n], 1.f);
    float v = buf[(long)n*32 + o] / c + bs[o];
    const float* xrow = &xin[(long)n*IN_C];
    #pragma unroll
    for (int i = 0; i < IN_C; ++i) v += xrow[i] * rs[i*32 + o];
    buf[(long)n*32 + o] = v;
    s += v; q += v*v;
  }
  s += __shfl_xor(s, 32); q += __shfl_xor(q, 32);
  int wv = tid >> 6;
  if ((tid & 63) < 32){ redS[wv][o] = s; redQ[wv][o] = q; }
  __syncthreads();
  if (tid < 32){
    float ts = 0.f, tq = 0.f;
    #pragma unroll
    for (int w = 0; w < 4; ++w){ ts += redS[w][tid]; tq += redQ[w][tid]; }
    atomicAdd(&stats[tid], ts); atomicAdd(&stats[32 + tid], tq);
  }
}

__launch_bounds__(256)
__global__ void bn_relu_k(float* __restrict__ buf, _Float16* __restrict__ bufh,
                          const float* __restrict__ stats,
                          const float* __restrict__ gg, const float* __restrict__ bb,
                          float invN, int total)
{
  int i = blockIdx.x*256 + threadIdx.x;
  if (i < total){
    int o = i & 31;
    float mu  = stats[o] * invN;
    float var = stats[32+o] * invN - mu*mu;
    float v = fmaxf((buf[i] - mu) * rsqrtf(var + 1e-5f) * gg[o] + bb[o], 0.f);
    buf[i]  = v;
    bufh[i] = (_Float16)v;
  }
}

__launch_bounds__(256)
__global__ void bn_pool_k(const float* __restrict__ buf, const float* __restrict__ stats,
                          const float* __restrict__ gg, const float* __restrict__ bb,
                          const int* __restrict__ batch, float* __restrict__ psum,
                          float* __restrict__ pcnt, float invN, int N)
{
  int tid = threadIdx.x;
  int o = tid & 31;
  int n = blockIdx.x*8 + (tid >> 5);
  if (n < N){
    int gr = batch[n];
    float mu  = stats[o] * invN;
    float var = stats[32+o] * invN - mu*mu;
    float v = fmaxf((buf[(long)n*32+o] - mu) * rsqrtf(var + 1e-5f) * gg[o] + bb[o], 0.f);
    atomicAdd(&psum[gr*32 + o], v);
    if (o == 0) atomicAdd(&pcnt[gr], 1.f);
  }
}

__launch_bounds__(256)
__global__ void final_k(const float* __restrict__ psum, const float* __restrict__ pcnt,
                        const float* __restrict__ gattr, const float* __restrict__ fcw,
                        const float* __restrict__ fcb, float* __restrict__ out, int G)
{
  int g = blockIdx.x*256 + threadIdx.x;
  if (g < G){
    float c = fmaxf(pcnt[g], 1.f);
    float o0 = fcb[0], o1 = fcb[1], o2 = fcb[2];
    #pragma unroll
    for (int j = 0; j < 32; ++j){
      float p = psum[g*32+j] / c;
      o0 += p*fcw[j*3+0]; o1 += p*fcw[j*3+1]; o2 += p*fcw[j*3+2];
    }
    #pragma unroll
    for (int j = 0; j < 4; ++j){
      float a = gattr[g*4+j];
      o0 += a*fcw[(32+j)*3+0]; o1 += a*fcw[(32+j)*3+1]; o2 += a*fcw[(32+j)*3+2];
    }
    out[g*3+0] = o0; out[g*3+1] = o1; out[g*3+2] = o2;
  }
}

// ---------------------------------------------------------------------------
extern "C" void kernel_launch(void* const* d_in, const int* in_sizes, int n_in,
                              void* d_out, int out_size, void* d_ws, size_t ws_size,
                              hipStream_t stream)
{
  const float* x     = (const float*)d_in[0];
  const int*   ei    = (const int*)  d_in[1];
  const float* ea    = (const float*)d_in[2];
  const int*   batch = (const int*)  d_in[3];
  const float* gattr = (const float*)d_in[4];
  const float* e1_w1 = (const float*)d_in[5];
  const float* e1_b1 = (const float*)d_in[6];
  const float* e1_w2 = (const float*)d_in[7];
  const float* e1_b2 = (const float*)d_in[8];
  const float* root1 = (const float*)d_in[9];
  const float* bias1 = (const float*)d_in[10];
  const float* bn1_g = (const float*)d_in[11];
  const float* bn1_b = (const float*)d_in[12];
  const float* e2_w1 = (const float*)d_in[13];
  const float* e2_b1 = (const float*)d_in[14];
  const float* e2_w2 = (const float*)d_in[15];
  const float* e2_b2 = (const float*)d_in[16];
  const float* root2 = (const float*)d_in[17];
  const float* bias2 = (const float*)d_in[18];
  const float* bn2_g = (const float*)d_in[19];
  const float* bn2_b = (const float*)d_in[20];
  const float* fc_w  = (const float*)d_in[21];
  const float* fc_b  = (const float*)d_in[22];
  float* out = (float*)d_out;

  float* ws = (float*)d_ws;
  const long NM = (long)NN*32;
  const int NBLK = (NN + 255) / 256;      // 196 scan blocks

  // ---- zeroed region (contiguous) ----
  float* bufA   = ws;                     // [N][32] conv1 agg -> h1
  float* bufB   = bufA + NM;              // [N][32] conv2 agg -> h2
  float* stats  = bufB + NM;              // 128
  float* psum   = stats + 128;            // [G][32]
  float* pcnt   = psum + GG*32;           // [G]
  int*   hist   = (int*)(pcnt + GG);      // [N] in-degree
  int*   cursor = hist + NN;              // [N]
  long zero_elems = 2*NM + 128 + GG*32 + GG + 2L*NN;
  // ---- non-zeroed scratch ----
  int*   part  = cursor + NN;             // [N]  local exclusive scan
  int*   blk   = part + NN;               // [256] block sums
  int*   esrc  = blk + 256;               // [E] sorted src
  int*   edst  = esrc + EE;               // [E] sorted dst
  float* eap   = (float*)(edst + EE);     // [E][5] sorted edge attr
  _Float16* bufAh = (_Float16*)(eap + (long)EE*5);  // [N][32] f16 of h1
  _Float16* xh    = bufAh + NM;           // [N][8] f16 of x
  _Float16* Bt1   = xh + (long)NN*8;      // [32][288]
  _Float16* Bt2   = Bt1 + 32*288;         // [32][1088]

  (void)hipMemsetAsync(d_ws, 0, (size_t)zero_elems * 4, stream);

  const int PREP_ELEMS = 32*288 + 32*1088 + NN*8;
  prep_k<<<(PREP_ELEMS + 255)/256, 256, 0, stream>>>(x, e1_w2, e1_b2, e2_w2, e2_b2,
                                                     xh, Bt1, Bt2);

  const int EGRID = (EE + 255)/256;       // 1954
  hist_k<<<EGRID, 256, 0, stream>>>(ei, hist);
  scan1_k<<<NBLK, 256, 0, stream>>>(hist, part, blk);
  scan2_k<<<1, 256, 0, stream>>>(blk, NBLK);
  scatter_k<<<EGRID, 256, 0, stream>>>(ei, ea, part, blk, cursor, esrc, edst, eap);

  const int EBLK = (EE + 127) / 128;      // 3907
  conv_msg_k<1><<<EBLK, 256, 0, stream>>>(xh, esrc, edst, eap, e1_w1, e1_b1, Bt1, bufA);
  node_update_k<6><<<256, 256, 0, stream>>>(x, root1, bias1, hist, bufA, stats, NN);
  bn_relu_k<<<(int)((NM + 255)/256), 256, 0, stream>>>(bufA, bufAh, stats, bn1_g, bn1_b,
                                                       1.f/NN, (int)NM);
  conv_msg_k<2><<<EBLK, 256, 0, stream>>>(bufAh, esrc, edst, eap, e2_w1, e2_b1, Bt2, bufB);
  node_update_k<32><<<256, 256, 0, stream>>>(bufA, root2, bias2, hist, bufB, stats + 64, NN);
  bn_pool_k<<<(NN + 7)/8, 256, 0, stream>>>(bufB, stats + 64, bn2_g, bn2_b, batch,
                                            psum, pcnt, 1.f/NN, NN);
  final_k<<<2, 256, 0, stream>>>(psum, pcnt, gattr, fc_w, fc_b, out, GG);
}

// Round 7
// 467.580 us; speedup vs baseline: 1.1910x; 1.1910x over previous
//
#include <hip/hip_runtime.h>

#define NN 50000
#define EE 500000
#define GG 512

typedef _Float16 f16x8 __attribute__((ext_vector_type(8)));
typedef _Float16 f16x2 __attribute__((ext_vector_type(2)));
typedef float f32x16 __attribute__((ext_vector_type(16)));

union F16x8U { f16x8 v8; f16x2 v2[4]; unsigned u[4]; };

__device__ __forceinline__ unsigned splat_h(float a){
  return __builtin_bit_cast(unsigned, __builtin_amdgcn_cvt_pkrtz(a, a));
}

// ---------------------------------------------------------------------------
// Prep: f16 tables (weights + x).
// ---------------------------------------------------------------------------
__launch_bounds__(256)
__global__ void prep_k(const float* __restrict__ x,
                       const float* __restrict__ w2a, const float* __restrict__ b2a,
                       const float* __restrict__ w2b, const float* __restrict__ b2b,
                       _Float16* __restrict__ xh, _Float16* __restrict__ Bt1,
                       _Float16* __restrict__ Bt2)
{
  int idx = blockIdx.x*256 + threadIdx.x;
  if (idx < 32*288){
    int o = idx / 288, ki = idx % 288;
    int k = ki >> 3, i = ki & 7;
    float v = 0.f;
    if (i < 6){
      if (k < 32)       v = w2a[k*192 + i*32 + o];
      else if (k == 32) v = b2a[i*32 + o];
    }
    Bt1[idx] = (_Float16)v;
  } else if (idx < 32*288 + 32*1088){
    int j = idx - 32*288;
    int o = j / 1088, ki = j % 1088;
    int k = ki >> 5, i = ki & 31;
    float v = 0.f;
    if (k < 32)       v = w2b[k*1024 + i*32 + o];
    else if (k == 32) v = b2b[i*32 + o];
    Bt2[j] = (_Float16)v;
  } else {
    int j = idx - (32*288 + 32*1088);
    if (j < NN*8){
      int n = j >> 3, i = j & 7;
      xh[j] = (_Float16)((i < 6) ? x[n*6 + i] : 0.f);
    }
  }
}

// ---------------------------------------------------------------------------
// Counting sort by dst: histogram -> 2-level exclusive scan -> scatter.
// ---------------------------------------------------------------------------
__launch_bounds__(256)
__global__ void hist_k(const int* __restrict__ ei, int* __restrict__ hist)
{
  int e = blockIdx.x*256 + threadIdx.x;
  if (e < EE) atomicAdd(&hist[ei[EE + e]], 1);
}

__launch_bounds__(256)
__global__ void scan1_k(const int* __restrict__ hist, int* __restrict__ part,
                        int* __restrict__ blk)
{
  __shared__ int s[256];
  int t = threadIdx.x, b = blockIdx.x, i = b*256 + t;
  int v = (i < NN) ? hist[i] : 0;
  s[t] = v; __syncthreads();
  #pragma unroll
  for (int off = 1; off < 256; off <<= 1){
    int u = (t >= off) ? s[t-off] : 0;
    __syncthreads();
    s[t] += u;
    __syncthreads();
  }
  if (i < NN) part[i] = s[t] - v;          // exclusive within block
  if (t == 255) blk[b] = s[255];           // block total
}

__launch_bounds__(256)
__global__ void scan2_k(int* __restrict__ blk, int nblk)
{
  __shared__ int s[256];
  int t = threadIdx.x;
  int v = (t < nblk) ? blk[t] : 0;
  s[t] = v; __syncthreads();
  #pragma unroll
  for (int off = 1; off < 256; off <<= 1){
    int u = (t >= off) ? s[t-off] : 0;
    __syncthreads();
    s[t] += u;
    __syncthreads();
  }
  if (t < nblk) blk[t] = s[t] - v;         // exclusive across blocks
}

__launch_bounds__(256)
__global__ void rowptr_k(const int* __restrict__ part, const int* __restrict__ blk,
                         int* __restrict__ rowptr)
{
  int n = blockIdx.x*256 + threadIdx.x;
  if (n < NN) rowptr[n] = part[n] + blk[n >> 8];
}

__launch_bounds__(256)
__global__ void scatter_k(const int* __restrict__ ei, const float* __restrict__ ea,
                          const int* __restrict__ rowptr, int* __restrict__ cursor,
                          int* __restrict__ esrc, int* __restrict__ edst,
                          float* __restrict__ eap)
{
  int e = blockIdx.x*256 + threadIdx.x;
  if (e < EE){
    int d = ei[EE + e];
    int slot = rowptr[d] + atomicAdd(&cursor[d], 1);
    esrc[slot] = ei[e];
    edst[slot] = d;
    #pragma unroll
    for (int q = 0; q < 5; ++q) eap[(long)slot*5 + q] = ea[(long)e*5 + q];
  }
}

// ---------------------------------------------------------------------------
// NNConv messages on dst-sorted edges: block = 128 edges (4 waves x 32),
// mfma 32x32x16 f16, then in-block segmented reduction in LDS and ONE
// store/atomic per (dst,col) per block.  Interior nodes (entire CSR range
// inside the block) use plain stores; boundary nodes use atomicAdd.
// D: col = lane&31, row = (reg&3) + 8*(reg>>2) + 4*(lane>>5).
// ---------------------------------------------------------------------------
template<int CONV>
__launch_bounds__(256, 8)
__global__ void conv_msg_k(const _Float16* __restrict__ xh,
                           const int* __restrict__ esrc,
                           const int* __restrict__ edst,
                           const float* __restrict__ eap,
                           const float* __restrict__ w1,
                           const float* __restrict__ b1,
                           const _Float16* __restrict__ Btg,
                           const int* __restrict__ rowptr,
                           const int* __restrict__ deg,
                           float* __restrict__ agg)
{
  constexpr int KP = (CONV == 1) ? 288 : 1088;
  constexpr int NT = KP / 16;
  __shared__ unsigned hs2[128][37];       // h' splats; reused as msg[128][37] floats
  __shared__ int segrow[130];
  __shared__ int segcnt[2];

  const int tid = threadIdx.x;
  const int e0  = blockIdx.x * 128;
  const int nvalid = (EE - e0 < 128) ? (EE - e0) : 128;

  // cooperative h' = relu(eap@w1 + b1), stored as splatted half2
  {
    int e  = tid >> 1;                    // 0..127
    int kb = (tid & 1) * 16;
    int eg = e0 + e;
    bool valid = eg < EE;
    float eav[5];
    #pragma unroll
    for (int q = 0; q < 5; ++q) eav[q] = valid ? eap[(long)eg*5 + q] : 0.f;
    #pragma unroll
    for (int k = kb; k < kb + 16; ++k){
      float a = b1[k];
      #pragma unroll
      for (int q = 0; q < 5; ++q) a += eav[q] * w1[q*32 + k];
      hs2[e][k] = splat_h(fmaxf(a, 0.f));
    }
    if (kb == 16){
      hs2[e][32] = splat_h(1.f);          // bias row (h' = 1)
      hs2[e][33] = 0u; hs2[e][34] = 0u; hs2[e][35] = 0u;
    }
  }
  __syncthreads();

  const int lane = tid & 63;
  const int wave = tid >> 6;
  const int col  = lane & 31;             // A-row (edge) AND B-col (output)
  const int hi   = lane >> 5;
  const int el   = wave*32 + col;         // block-local edge for A
  const int emy  = e0 + el;
  const int src  = (emy < EE) ? esrc[emy] : 0;

  // x fragments (f16 pairs), register-resident
  F16x8U xa, xb;
  if (CONV == 1){
    xa.v8 = *(const f16x8*)(xh + (long)src*8);
    xb.v8 = xa.v8;
  } else {
    xa.v8 = *(const f16x8*)(xh + (long)src*32 + 8*hi);
    xb.v8 = *(const f16x8*)(xh + (long)src*32 + 16 + 8*hi);
  }

  // h' splats, register-resident (static indexing under full unroll)
  unsigned h2[(CONV == 1) ? 18 : 34];
  if (CONV == 1){
    #pragma unroll
    for (int t = 0; t < 18; ++t) h2[t] = hs2[el][2*t + hi];
  } else {
    #pragma unroll
    for (int kk = 0; kk < 34; ++kk) h2[kk] = hs2[el][kk];
  }

  f32x16 acc;
  #pragma unroll
  for (int r = 0; r < 16; ++r) acc[r] = 0.f;

  const _Float16* bp = Btg + (long)col*KP + 8*hi;
  #pragma unroll
  for (int t = 0; t < NT; ++t){
    f16x8 bf = *(const f16x8*)(bp + 16*t);
    f16x2 hv = __builtin_bit_cast(f16x2, h2[(CONV == 1) ? t : (t >> 1)]);
    const F16x8U& xs = (CONV == 1) ? xa : ((t & 1) ? xb : xa);
    F16x8U af;
    #pragma unroll
    for (int p = 0; p < 4; ++p) af.v2[p] = hv * xs.v2[p];
    acc = __builtin_amdgcn_mfma_f32_32x32x16_f16(af.v8, bf, acc, 0, 0, 0);
  }

  __syncthreads();                        // all waves done reading hs2 -> reuse as msg
  float* msg = (float*)&hs2[0][0];        // [128][37] (odd stride, bank-friendly)

  #pragma unroll
  for (int g = 0; g < 4; ++g){
    #pragma unroll
    for (int r = 0; r < 4; ++r){
      int row = wave*32 + r + 8*g + 4*hi;
      msg[row*37 + col] = acc[4*g + r];
    }
  }

  // segment detection over the 128 sorted edges (waves 0,1)
  bool st = false;
  if (tid < 128){
    int eg = e0 + tid;
    st = (tid < nvalid) && (tid == 0 || edst[eg] != edst[eg-1]);
  }
  unsigned long long m = __ballot(st);
  int rank = __popcll(m & ((1ull << lane) - 1ull));
  if (tid < 128 && lane == 0) segcnt[wave] = (int)__popcll(m);
  __syncthreads();
  if (st) segrow[rank + ((tid >= 64) ? segcnt[0] : 0)] = tid;
  if (tid == 128) segrow[segcnt[0] + segcnt[1]] = nvalid;   // sentinel
  __syncthreads();

  // segmented sum + one write per (dst, col)
  const int nseg = segcnt[0] + segcnt[1];
  const int c = tid & 31;
  for (int s = tid >> 5; s < nseg; s += 8){
    int r0 = segrow[s], r1 = segrow[s+1];
    float sum = 0.f;
    for (int r = r0; r < r1; ++r) sum += msg[r*37 + c];
    int d  = edst[e0 + r0];
    int rp = rowptr[d];
    if (rp >= e0 && rp + deg[d] <= e0 + nvalid)
      agg[(long)d*32 + c] = sum;          // node fully inside this block
    else
      atomicAdd(&agg[(long)d*32 + c], sum);
  }
}

// ---------------------------------------------------------------------------
// h = agg/max(cnt,1) + x@root + bias (in place), accumulate BN stats.
// ---------------------------------------------------------------------------
template<int IN_C>
__launch_bounds__(256)
__global__ void node_update_k(const float* __restrict__ xin, const float* __restrict__ root,
                              const float* __restrict__ bias, const int* __restrict__ cnt,
                              float* __restrict__ buf, float* __restrict__ stats, int N)
{
  __shared__ float rs[IN_C*32];
  __shared__ float bs[32];
  __shared__ float redS[4][32], redQ[4][32];
  int tid = threadIdx.x;
  for (int i = tid; i < IN_C*32; i += 256) rs[i] = root[i];
  if (tid < 32) bs[tid] = bias[tid];
  __syncthreads();
  int o = tid & 31, slot = tid >> 5;
  float s = 0.f, q = 0.f;
  for (int n = blockIdx.x*8 + slot; n < N; n += gridDim.x*8){
    float c = fmaxf((float)cnt[n], 1.f);
    float v = buf[(long)n*32 + o] / c + bs[o];
    const float* xrow = &xin[(long)n*IN_C];
    #pragma unroll
    for (int i = 0; i < IN_C; ++i) v += xrow[i] * rs[i*32 + o];
    buf[(long)n*32 + o] = v;
    s += v; q += v*v;
  }
  s += __shfl_xor(s, 32); q += __shfl_xor(q, 32);
  int wv = tid >> 6;
  if ((tid & 63) < 32){ redS[wv][o] = s; redQ[wv][o] = q; }
  __syncthreads();
  if (tid < 32){
    float ts = 0.f, tq = 0.f;
    #pragma unroll
    for (int w = 0; w < 4; ++w){ ts += redS[w][tid]; tq += redQ[w][tid]; }
    atomicAdd(&stats[tid], ts); atomicAdd(&stats[32 + tid], tq);
  }
}

__launch_bounds__(256)
__global__ void bn_relu_k(float* __restrict__ buf, _Float16* __restrict__ bufh,
                          const float* __restrict__ stats,
                          const float* __restrict__ gg, const float* __restrict__ bb,
                          float invN, int total)
{
  int i = blockIdx.x*256 + threadIdx.x;
  if (i < total){
    int o = i & 31;
    float mu  = stats[o] * invN;
    float var = stats[32+o] * invN - mu*mu;
    float v = fmaxf((buf[i] - mu) * rsqrtf(var + 1e-5f) * gg[o] + bb[o], 0.f);
    buf[i]  = v;
    bufh[i] = (_Float16)v;
  }
}

__launch_bounds__(256)
__global__ void bn_pool_k(const float* __restrict__ buf, const float* __restrict__ stats,
                          const float* __restrict__ gg, const float* __restrict__ bb,
                          const int* __restrict__ batch, float* __restrict__ psum,
                          float* __restrict__ pcnt, float invN, int N)
{
  int tid = threadIdx.x;
  int o = tid & 31;
  int n = blockIdx.x*8 + (tid >> 5);
  if (n < N){
    int gr = batch[n];
    float mu  = stats[o] * invN;
    float var = stats[32+o] * invN - mu*mu;
    float v = fmaxf((buf[(long)n*32+o] - mu) * rsqrtf(var + 1e-5f) * gg[o] + bb[o], 0.f);
    atomicAdd(&psum[gr*32 + o], v);
    if (o == 0) atomicAdd(&pcnt[gr], 1.f);
  }
}

__launch_bounds__(256)
__global__ void final_k(const float* __restrict__ psum, const float* __restrict__ pcnt,
                        const float* __restrict__ gattr, const float* __restrict__ fcw,
                        const float* __restrict__ fcb, float* __restrict__ out, int G)
{
  int g = blockIdx.x*256 + threadIdx.x;
  if (g < G){
    float c = fmaxf(pcnt[g], 1.f);
    float o0 = fcb[0], o1 = fcb[1], o2 = fcb[2];
    #pragma unroll
    for (int j = 0; j < 32; ++j){
      float p = psum[g*32+j] / c;
      o0 += p*fcw[j*3+0]; o1 += p*fcw[j*3+1]; o2 += p*fcw[j*3+2];
    }
    #pragma unroll
    for (int j = 0; j < 4; ++j){
      float a = gattr[g*4+j];
      o0 += a*fcw[(32+j)*3+0]; o1 += a*fcw[(32+j)*3+1]; o2 += a*fcw[(32+j)*3+2];
    }
    out[g*3+0] = o0; out[g*3+1] = o1; out[g*3+2] = o2;
  }
}

// ---------------------------------------------------------------------------
extern "C" void kernel_launch(void* const* d_in, const int* in_sizes, int n_in,
                              void* d_out, int out_size, void* d_ws, size_t ws_size,
                              hipStream_t stream)
{
  const float* x     = (const float*)d_in[0];
  const int*   ei    = (const int*)  d_in[1];
  const float* ea    = (const float*)d_in[2];
  const int*   batch = (const int*)  d_in[3];
  const float* gattr = (const float*)d_in[4];
  const float* e1_w1 = (const float*)d_in[5];
  const float* e1_b1 = (const float*)d_in[6];
  const float* e1_w2 = (const float*)d_in[7];
  const float* e1_b2 = (const float*)d_in[8];
  const float* root1 = (const float*)d_in[9];
  const float* bias1 = (const float*)d_in[10];
  const float* bn1_g = (const float*)d_in[11];
  const float* bn1_b = (const float*)d_in[12];
  const float* e2_w1 = (const float*)d_in[13];
  const float* e2_b1 = (const float*)d_in[14];
  const float* e2_w2 = (const float*)d_in[15];
  const float* e2_b2 = (const float*)d_in[16];
  const float* root2 = (const float*)d_in[17];
  const float* bias2 = (const float*)d_in[18];
  const float* bn2_g = (const float*)d_in[19];
  const float* bn2_b = (const float*)d_in[20];
  const float* fc_w  = (const float*)d_in[21];
  const float* fc_b  = (const float*)d_in[22];
  float* out = (float*)d_out;

  float* ws = (float*)d_ws;
  const long NM = (long)NN*32;
  const int NBLK = (NN + 255) / 256;      // 196 scan blocks

  // ---- zeroed region (contiguous) ----
  float* bufA   = ws;                     // [N][32] conv1 agg -> h1
  float* bufB   = bufA + NM;              // [N][32] conv2 agg -> h2
  float* stats  = bufB + NM;              // 128
  float* psum   = stats + 128;            // [G][32]
  float* pcnt   = psum + GG*32;           // [G]
  int*   hist   = (int*)(pcnt + GG);      // [N] in-degree
  int*   cursor = hist + NN;              // [N]
  long zero_elems = 2*NM + 128 + GG*32 + GG + 2L*NN;
  // ---- non-zeroed scratch ----
  int*   part   = cursor + NN;            // [N]  local exclusive scan
  int*   blk    = part + NN;              // [256] block sums
  int*   rowptr = blk + 256;              // [N] CSR row pointer
  int*   esrc   = rowptr + NN;            // [E] sorted src
  int*   edst   = esrc + EE;              // [E] sorted dst
  float* eap    = (float*)(edst + EE);    // [E][5] sorted edge attr
  _Float16* bufAh = (_Float16*)(eap + (long)EE*5);  // [N][32] f16 of h1
  _Float16* xh    = bufAh + NM;           // [N][8] f16 of x
  _Float16* Bt1   = xh + (long)NN*8;      // [32][288]
  _Float16* Bt2   = Bt1 + 32*288;         // [32][1088]

  (void)hipMemsetAsync(d_ws, 0, (size_t)zero_elems * 4, stream);

  const int PREP_ELEMS = 32*288 + 32*1088 + NN*8;
  prep_k<<<(PREP_ELEMS + 255)/256, 256, 0, stream>>>(x, e1_w2, e1_b2, e2_w2, e2_b2,
                                                     xh, Bt1, Bt2);

  const int EGRID = (EE + 255)/256;       // 1954
  hist_k<<<EGRID, 256, 0, stream>>>(ei, hist);
  scan1_k<<<NBLK, 256, 0, stream>>>(hist, part, blk);
  scan2_k<<<1, 256, 0, stream>>>(blk, NBLK);
  rowptr_k<<<NBLK, 256, 0, stream>>>(part, blk, rowptr);
  scatter_k<<<EGRID, 256, 0, stream>>>(ei, ea, rowptr, cursor, esrc, edst, eap);

  const int EBLK = (EE + 127) / 128;      // 3907
  conv_msg_k<1><<<EBLK, 256, 0, stream>>>(xh, esrc, edst, eap, e1_w1, e1_b1, Bt1,
                                          rowptr, hist, bufA);
  node_update_k<6><<<256, 256, 0, stream>>>(x, root1, bias1, hist, bufA, stats, NN);
  bn_relu_k<<<(int)((NM + 255)/256), 256, 0, stream>>>(bufA, bufAh, stats, bn1_g, bn1_b,
                                                       1.f/NN, (int)NM);
  conv_msg_k<2><<<EBLK, 256, 0, stream>>>(bufAh, esrc, edst, eap, e2_w1, e2_b1, Bt2,
                                          rowptr, hist, bufB);
  node_update_k<32><<<256, 256, 0, stream>>>(bufA, root2, bias2, hist, bufB, stats + 64, NN);
  bn_pool_k<<<(NN + 7)/8, 256, 0, stream>>>(bufB, stats + 64, bn2_g, bn2_b, batch,
                                            psum, pcnt, 1.f/NN, NN);
  final_k<<<2, 256, 0, stream>>>(psum, pcnt, gattr, fc_w, fc_b, out, GG);
}

// Round 9
// 379.627 us; speedup vs baseline: 1.4670x; 1.2317x over previous
//
#include <hip/hip_runtime.h>

#define NN 50000
#define EE 500000
#define GG 512

typedef _Float16 f16x8 __attribute__((ext_vector_type(8)));
typedef _Float16 f16x2 __attribute__((ext_vector_type(2)));
typedef float f32x16 __attribute__((ext_vector_type(16)));

union F16x8U { f16x8 v8; f16x2 v2[4]; unsigned u[4]; };

__device__ __forceinline__ unsigned splat_h(float a){
  return __builtin_bit_cast(unsigned, __builtin_amdgcn_cvt_pkrtz(a, a));
}

// async global->LDS, 16B per lane; LDS dest = wave-uniform base + lane*16
__device__ __forceinline__ void gload16(const _Float16* g, _Float16* l){
  __builtin_amdgcn_global_load_lds(
      (const __attribute__((address_space(1))) unsigned int*)g,
      (__attribute__((address_space(3))) unsigned int*)l, 16, 0, 0);
}

// ---------------------------------------------------------------------------
// Prep: f16 tables in COALESCED lane-major layout.
//  BtL[t][lane][8]: lane=(hi<<5)|col reads ki = 16t + 8hi + j for column col.
//  conv1: 20 slices (18 used, KP=288, k=ki>>3, i=ki&7)
//  conv2: 72 slices (68 used, KP=1088, k=ki>>5, i=ki&31)
//  xh[n][8] = f16(x[n][0..5]), pads 0
// ---------------------------------------------------------------------------
#define NL1 (20*512)
#define NL2 (72*512)
__launch_bounds__(256)
__global__ void prep_k(const float* __restrict__ x,
                       const float* __restrict__ w2a, const float* __restrict__ b2a,
                       const float* __restrict__ w2b, const float* __restrict__ b2b,
                       _Float16* __restrict__ xh, _Float16* __restrict__ BtL1,
                       _Float16* __restrict__ BtL2)
{
  int idx = blockIdx.x*256 + threadIdx.x;
  if (idx < NL1){
    int t = idx >> 9, r = idx & 511;
    int lane = r >> 3, j = r & 7;
    int col = lane & 31, hi = lane >> 5;
    int ki = 16*t + 8*hi + j;
    int k = ki >> 3, i = ki & 7;
    float v = 0.f;
    if (i < 6){
      if (k < 32)       v = w2a[k*192 + i*32 + col];
      else if (k == 32) v = b2a[i*32 + col];
    }
    BtL1[idx] = (_Float16)v;
  } else if (idx < NL1 + NL2){
    int q = idx - NL1;
    int t = q >> 9, r = q & 511;
    int lane = r >> 3, j = r & 7;
    int col = lane & 31, hi = lane >> 5;
    int ki = 16*t + 8*hi + j;
    int k = ki >> 5, i = ki & 31;
    float v = 0.f;
    if (k < 32)       v = w2b[k*1024 + i*32 + col];
    else if (k == 32) v = b2b[i*32 + col];
    BtL2[q] = (_Float16)v;
  } else {
    int j = idx - (NL1 + NL2);
    if (j < NN*8){
      int n = j >> 3, i = j & 7;
      xh[j] = (_Float16)((i < 6) ? x[n*6 + i] : 0.f);
    }
  }
}

// ---------------------------------------------------------------------------
// Counting sort by dst: histogram -> 2-level exclusive scan -> scatter.
// ---------------------------------------------------------------------------
__launch_bounds__(256)
__global__ void hist_k(const int* __restrict__ ei, int* __restrict__ hist)
{
  int e = blockIdx.x*256 + threadIdx.x;
  if (e < EE) atomicAdd(&hist[ei[EE + e]], 1);
}

__launch_bounds__(256)
__global__ void scan1_k(const int* __restrict__ hist, int* __restrict__ part,
                        int* __restrict__ blk)
{
  __shared__ int s[256];
  int t = threadIdx.x, b = blockIdx.x, i = b*256 + t;
  int v = (i < NN) ? hist[i] : 0;
  s[t] = v; __syncthreads();
  #pragma unroll
  for (int off = 1; off < 256; off <<= 1){
    int u = (t >= off) ? s[t-off] : 0;
    __syncthreads();
    s[t] += u;
    __syncthreads();
  }
  if (i < NN) part[i] = s[t] - v;          // exclusive within block
  if (t == 255) blk[b] = s[255];           // block total
}

__launch_bounds__(256)
__global__ void scan2_k(int* __restrict__ blk, int nblk)
{
  __shared__ int s[256];
  int t = threadIdx.x;
  int v = (t < nblk) ? blk[t] : 0;
  s[t] = v; __syncthreads();
  #pragma unroll
  for (int off = 1; off < 256; off <<= 1){
    int u = (t >= off) ? s[t-off] : 0;
    __syncthreads();
    s[t] += u;
    __syncthreads();
  }
  if (t < nblk) blk[t] = s[t] - v;         // exclusive across blocks
}

__launch_bounds__(256)
__global__ void rowptr_k(const int* __restrict__ part, const int* __restrict__ blk,
                         int* __restrict__ rowptr)
{
  int n = blockIdx.x*256 + threadIdx.x;
  if (n < NN) rowptr[n] = part[n] + blk[n >> 8];
}

__launch_bounds__(256)
__global__ void scatter_k(const int* __restrict__ ei, const float* __restrict__ ea,
                          const int* __restrict__ rowptr, int* __restrict__ cursor,
                          int* __restrict__ esrc, int* __restrict__ edst,
                          float* __restrict__ eap)
{
  int e = blockIdx.x*256 + threadIdx.x;
  if (e < EE){
    int d = ei[EE + e];
    int slot = rowptr[d] + atomicAdd(&cursor[d], 1);
    esrc[slot] = ei[e];
    edst[slot] = d;
    #pragma unroll
    for (int q = 0; q < 5; ++q) eap[(long)slot*5 + q] = ea[(long)e*5 + q];
  }
}

// ---------------------------------------------------------------------------
// NNConv messages on dst-sorted edges: block = 128 edges (4 waves x 32),
// mfma 32x32x16 f16.  B staged in LDS via global_load_lds (coalesced layout,
// shared by all 4 waves; conv2 double-buffered 8-slice chunks).  Then
// in-block segmented reduction and ONE store/atomic per (dst,col).
// D: col = lane&31, row = (reg&3) + 8*(reg>>2) + 4*(lane>>5).
// ---------------------------------------------------------------------------
template<int CONV>
__launch_bounds__(256, 4)
__global__ void conv_msg_k(const _Float16* __restrict__ xh,
                           const int* __restrict__ esrc,
                           const int* __restrict__ edst,
                           const float* __restrict__ eap,
                           const float* __restrict__ w1,
                           const float* __restrict__ b1,
                           const _Float16* __restrict__ Btg,
                           const int* __restrict__ rowptr,
                           const int* __restrict__ deg,
                           float* __restrict__ agg)
{
  constexpr int BTB_F16 = (CONV == 1) ? 10240 : 8192;   // 20KB / 2x8KB
  __shared__ unsigned hs2[128][37];       // h' splats; reused as msg[128][37] floats
  __shared__ _Float16 btb[BTB_F16];
  __shared__ int segrow[130];
  __shared__ int segcnt[2];

  const int tid  = threadIdx.x;
  const int lane = tid & 63;
  const int wave = tid >> 6;
  const int e0   = blockIdx.x * 128;
  const int nvalid = (EE - e0 < 128) ? (EE - e0) : 128;

  // issue stage of first chunk (conv1: whole 20-slice table) before h' phase
  if (CONV == 1){
    #pragma unroll
    for (int i = 0; i < 5; ++i)
      gload16(Btg + (wave + 4*i)*512 + lane*8, btb + (wave + 4*i)*512);
  } else {
    gload16(Btg + wave*512 + lane*8,       btb + wave*512);
    gload16(Btg + (wave + 4)*512 + lane*8, btb + (wave + 4)*512);
  }

  // cooperative h' = relu(eap@w1 + b1), stored as splatted half2
  {
    int e  = tid >> 1;                    // 0..127
    int kb = (tid & 1) * 16;
    int eg = e0 + e;
    bool valid = eg < EE;
    float eav[5];
    #pragma unroll
    for (int q = 0; q < 5; ++q) eav[q] = valid ? eap[(long)eg*5 + q] : 0.f;
    #pragma unroll
    for (int k = kb; k < kb + 16; ++k){
      float a = b1[k];
      #pragma unroll
      for (int q = 0; q < 5; ++q) a += eav[q] * w1[q*32 + k];
      hs2[e][k] = splat_h(fmaxf(a, 0.f));
    }
    if (kb == 16){
      hs2[e][32] = splat_h(1.f);          // bias row (h' = 1)
      hs2[e][33] = 0u; hs2[e][34] = 0u; hs2[e][35] = 0u;
    }
  }
  __syncthreads();                        // hs2 ready AND first stage drained

  const int col = lane & 31;              // A-row (edge) AND B-col (output)
  const int hi  = lane >> 5;
  const int el  = wave*32 + col;          // block-local edge for A
  const int emy = e0 + el;
  const int src = (emy < EE) ? esrc[emy] : 0;

  // x fragments (f16 pairs), register-resident
  F16x8U xa, xb;
  if (CONV == 1){
    xa.v8 = *(const f16x8*)(xh + (long)src*8);
    xb.v8 = xa.v8;
  } else {
    xa.v8 = *(const f16x8*)(xh + (long)src*32 + 8*hi);
    xb.v8 = *(const f16x8*)(xh + (long)src*32 + 16 + 8*hi);
  }

  // h' splats, register-resident (static indexing under full unroll)
  unsigned h2[(CONV == 1) ? 18 : 34];
  if (CONV == 1){
    #pragma unroll
    for (int t = 0; t < 18; ++t) h2[t] = hs2[el][2*t + hi];
  } else {
    #pragma unroll
    for (int kk = 0; kk < 34; ++kk) h2[kk] = hs2[el][kk];
  }

  f32x16 acc;
  #pragma unroll
  for (int r = 0; r < 16; ++r) acc[r] = 0.f;

  if (CONV == 1){
    #pragma unroll
    for (int t = 0; t < 18; ++t){
      f16x8 bf = *(const f16x8*)&btb[t*512 + lane*8];
      f16x2 hv = __builtin_bit_cast(f16x2, h2[t]);
      F16x8U af;
      #pragma unroll
      for (int p = 0; p < 4; ++p) af.v2[p] = hv * xa.v2[p];
      acc = __builtin_amdgcn_mfma_f32_32x32x16_f16(af.v8, bf, acc, 0, 0, 0);
    }
    __syncthreads();                      // all reads of hs2/btb done
  } else {
    // 9 chunks of 8 slices (last uses 4), double-buffered
    #pragma unroll
    for (int c = 0; c < 9; ++c){
      if (c < 8){                         // stage chunk c+1 into buf (c+1)&1
        const _Float16* gs = Btg + (long)((c+1)*8 + wave)*512 + lane*8;
        _Float16* ls = btb + ((c+1)&1)*4096 + wave*512;
        gload16(gs, ls);
        gload16(gs + 4*512, ls + 4*512);
      }
      const int tmax = (c == 8) ? 4 : 8;
      #pragma unroll
      for (int tt = 0; tt < tmax; ++tt){
        const int t = c*8 + tt;
        f16x8 bf = *(const f16x8*)&btb[(c&1)*4096 + tt*512 + lane*8];
        f16x2 hv = __builtin_bit_cast(f16x2, h2[t >> 1]);
        const F16x8U& xs = (t & 1) ? xb : xa;
        F16x8U af;
        #pragma unroll
        for (int p = 0; p < 4; ++p) af.v2[p] = hv * xs.v2[p];
        acc = __builtin_amdgcn_mfma_f32_32x32x16_f16(af.v8, bf, acc, 0, 0, 0);
      }
      __syncthreads();                    // stage drained + buffer reads done
    }
  }

  float* msg = (float*)&hs2[0][0];        // reuse as [128][37]

  #pragma unroll
  for (int g = 0; g < 4; ++g){
    #pragma unroll
    for (int r = 0; r < 4; ++r){
      int row = wave*32 + r + 8*g + 4*hi;
      msg[row*37 + col] = acc[4*g + r];
    }
  }

  // segment detection over the 128 sorted edges (waves 0,1)
  bool st = false;
  if (tid < 128){
    int eg = e0 + tid;
    st = (tid < nvalid) && (tid == 0 || edst[eg] != edst[eg-1]);
  }
  unsigned long long m = __ballot(st);
  int rank = __popcll(m & ((1ull << lane) - 1ull));
  if (tid < 128 && lane == 0) segcnt[wave] = (int)__popcll(m);
  __syncthreads();
  if (st) segrow[rank + ((tid >= 64) ? segcnt[0] : 0)] = tid;
  if (tid == 128) segrow[segcnt[0] + segcnt[1]] = nvalid;   // sentinel
  __syncthreads();

  // segmented sum + one write per (dst, col)
  const int nseg = segcnt[0] + segcnt[1];
  const int c2 = tid & 31;
  for (int s = tid >> 5; s < nseg; s += 8){
    int r0 = segrow[s], r1 = segrow[s+1];
    float sum = 0.f;
    for (int r = r0; r < r1; ++r) sum += msg[r*37 + c2];
    int d  = edst[e0 + r0];
    int rp = rowptr[d];
    if (rp >= e0 && rp + deg[d] <= e0 + nvalid)
      agg[(long)d*32 + c2] = sum;         // node fully inside this block
    else
      atomicAdd(&agg[(long)d*32 + c2], sum);
  }
}

// ---------------------------------------------------------------------------
// h = agg/max(cnt,1) + x@root + bias (in place), accumulate BN stats.
// ---------------------------------------------------------------------------
template<int IN_C>
__launch_bounds__(256)
__global__ void node_update_k(const float* __restrict__ xin, const float* __restrict__ root,
                              const float* __restrict__ bias, const int* __restrict__ cnt,
                              float* __restrict__ buf, float* __restrict__ stats, int N)
{
  __shared__ float rs[IN_C*32];
  __shared__ float bs[32];
  __shared__ float redS[4][32], redQ[4][32];
  int tid = threadIdx.x;
  for (int i = tid; i < IN_C*32; i += 256) rs[i] = root[i];
  if (tid < 32) bs[tid] = bias[tid];
  __syncthreads();
  int o = tid & 31, slot = tid >> 5;
  float s = 0.f, q = 0.f;
  for (int n = blockIdx.x*8 + slot; n < N; n += gridDim.x*8){
    float c = fmaxf((float)cnt[n], 1.f);
    float v = buf[(long)n*32 + o] / c + bs[o];
    const float* xrow = &xin[(long)n*IN_C];
    #pragma unroll
    for (int i = 0; i < IN_C; ++i) v += xrow[i] * rs[i*32 + o];
    buf[(long)n*32 + o] = v;
    s += v; q += v*v;
  }
  s += __shfl_xor(s, 32); q += __shfl_xor(q, 32);
  int wv = tid >> 6;
  if ((tid & 63) < 32){ redS[wv][o] = s; redQ[wv][o] = q; }
  __syncthreads();
  if (tid < 32){
    float ts = 0.f, tq = 0.f;
    #pragma unroll
    for (int w = 0; w < 4; ++w){ ts += redS[w][tid]; tq += redQ[w][tid]; }
    atomicAdd(&stats[tid], ts); atomicAdd(&stats[32 + tid], tq);
  }
}

__launch_bounds__(256)
__global__ void bn_relu_k(float* __restrict__ buf, _Float16* __restrict__ bufh,
                          const float* __restrict__ stats,
                          const float* __restrict__ gg, const float* __restrict__ bb,
                          float invN, int total)
{
  int i = blockIdx.x*256 + threadIdx.x;
  if (i < total){
    int o = i & 31;
    float mu  = stats[o] * invN;
    float var = stats[32+o] * invN - mu*mu;
    float v = fmaxf((buf[i] - mu) * rsqrtf(var + 1e-5f) * gg[o] + bb[o], 0.f);
    buf[i]  = v;
    bufh[i] = (_Float16)v;
  }
}

__launch_bounds__(256)
__global__ void bn_pool_k(const float* __restrict__ buf, const float* __restrict__ stats,
                          const float* __restrict__ gg, const float* __restrict__ bb,
                          const int* __restrict__ batch, float* __restrict__ psum,
                          float* __restrict__ pcnt, float invN, int N)
{
  int tid = threadIdx.x;
  int o = tid & 31;
  int n = blockIdx.x*8 + (tid >> 5);
  if (n < N){
    int gr = batch[n];
    float mu  = stats[o] * invN;
    float var = stats[32+o] * invN - mu*mu;
    float v = fmaxf((buf[(long)n*32+o] - mu) * rsqrtf(var + 1e-5f) * gg[o] + bb[o], 0.f);
    atomicAdd(&psum[gr*32 + o], v);
    if (o == 0) atomicAdd(&pcnt[gr], 1.f);
  }
}

__launch_bounds__(256)
__global__ void final_k(const float* __restrict__ psum, const float* __restrict__ pcnt,
                        const float* __restrict__ gattr, const float* __restrict__ fcw,
                        const float* __restrict__ fcb, float* __restrict__ out, int G)
{
  int g = blockIdx.x*256 + threadIdx.x;
  if (g < G){
    float c = fmaxf(pcnt[g], 1.f);
    float o0 = fcb[0], o1 = fcb[1], o2 = fcb[2];
    #pragma unroll
    for (int j = 0; j < 32; ++j){
      float p = psum[g*32+j] / c;
      o0 += p*fcw[j*3+0]; o1 += p*fcw[j*3+1]; o2 += p*fcw[j*3+2];
    }
    #pragma unroll
    for (int j = 0; j < 4; ++j){
      float a = gattr[g*4+j];
      o0 += a*fcw[(32+j)*3+0]; o1 += a*fcw[(32+j)*3+1]; o2 += a*fcw[(32+j)*3+2];
    }
    out[g*3+0] = o0; out[g*3+1] = o1; out[g*3+2] = o2;
  }
}

// ---------------------------------------------------------------------------
extern "C" void kernel_launch(void* const* d_in, const int* in_sizes, int n_in,
                              void* d_out, int out_size, void* d_ws, size_t ws_size,
                              hipStream_t stream)
{
  const float* x     = (const float*)d_in[0];
  const int*   ei    = (const int*)  d_in[1];
  const float* ea    = (const float*)d_in[2];
  const int*   batch = (const int*)  d_in[3];
  const float* gattr = (const float*)d_in[4];
  const float* e1_w1 = (const float*)d_in[5];
  const float* e1_b1 = (const float*)d_in[6];
  const float* e1_w2 = (const float*)d_in[7];
  const float* e1_b2 = (const float*)d_in[8];
  const float* root1 = (const float*)d_in[9];
  const float* bias1 = (const float*)d_in[10];
  const float* bn1_g = (const float*)d_in[11];
  const float* bn1_b = (const float*)d_in[12];
  const float* e2_w1 = (const float*)d_in[13];
  const float* e2_b1 = (const float*)d_in[14];
  const float* e2_w2 = (const float*)d_in[15];
  const float* e2_b2 = (const float*)d_in[16];
  const float* root2 = (const float*)d_in[17];
  const float* bias2 = (const float*)d_in[18];
  const float* bn2_g = (const float*)d_in[19];
  const float* bn2_b = (const float*)d_in[20];
  const float* fc_w  = (const float*)d_in[21];
  const float* fc_b  = (const float*)d_in[22];
  float* out = (float*)d_out;

  float* ws = (float*)d_ws;
  const long NM = (long)NN*32;
  const int NBLK = (NN + 255) / 256;      // 196 scan blocks

  // ---- zeroed region (contiguous) ----
  float* bufA   = ws;                     // [N][32] conv1 agg -> h1
  float* bufB   = bufA + NM;              // [N][32] conv2 agg -> h2
  float* stats  = bufB + NM;              // 128
  float* psum   = stats + 128;            // [G][32]
  float* pcnt   = psum + GG*32;           // [G]
  int*   hist   = (int*)(pcnt + GG);      // [N] in-degree
  int*   cursor = hist + NN;              // [N]
  long zero_elems = 2*NM + 128 + GG*32 + GG + 2L*NN;
  // ---- non-zeroed scratch ----
  int*   part   = cursor + NN;            // [N]  local exclusive scan
  int*   blk    = part + NN;              // [256] block sums
  int*   rowptr = blk + 256;              // [N] CSR row pointer
  int*   esrc   = rowptr + NN;            // [E] sorted src
  int*   edst   = esrc + EE;              // [E] sorted dst
  float* eap    = (float*)(edst + EE);    // [E][5] sorted edge attr
  _Float16* bufAh = (_Float16*)(eap + (long)EE*5);  // [N][32] f16 of h1
  _Float16* xh    = bufAh + NM;           // [N][8] f16 of x
  _Float16* BtL1  = xh + (long)NN*8;      // [20][64][8] coalesced
  _Float16* BtL2  = BtL1 + NL1;           // [72][64][8] coalesced

  (void)hipMemsetAsync(d_ws, 0, (size_t)zero_elems * 4, stream);

  const int PREP_ELEMS = NL1 + NL2 + NN*8;
  prep_k<<<(PREP_ELEMS + 255)/256, 256, 0, stream>>>(x, e1_w2, e1_b2, e2_w2, e2_b2,
                                                     xh, BtL1, BtL2);

  const int EGRID = (EE + 255)/256;       // 1954
  hist_k<<<EGRID, 256, 0, stream>>>(ei, hist);
  scan1_k<<<NBLK, 256, 0, stream>>>(hist, part, blk);
  scan2_k<<<1, 256, 0, stream>>>(blk, NBLK);
  rowptr_k<<<NBLK, 256, 0, stream>>>(part, blk, rowptr);
  scatter_k<<<EGRID, 256, 0, stream>>>(ei, ea, rowptr, cursor, esrc, edst, eap);

  const int EBLK = (EE + 127) / 128;      // 3907
  conv_msg_k<1><<<EBLK, 256, 0, stream>>>(xh, esrc, edst, eap, e1_w1, e1_b1, BtL1,
                                          rowptr, hist, bufA);
  node_update_k<6><<<256, 256, 0, stream>>>(x, root1, bias1, hist, bufA, stats, NN);
  bn_relu_k<<<(int)((NM + 255)/256), 256, 0, stream>>>(bufA, bufAh, stats, bn1_g, bn1_b,
                                                       1.f/NN, (int)NM);
  conv_msg_k<2><<<EBLK, 256, 0, stream>>>(bufAh, esrc, edst, eap, e2_w1, e2_b1, BtL2,
                                          rowptr, hist, bufB);
  node_update_k<32><<<256, 256, 0, stream>>>(bufA, root2, bias2, hist, bufB, stats + 64, NN);
  bn_pool_k<<<(NN + 7)/8, 256, 0, stream>>>(bufB, stats + 64, bn2_g, bn2_b, batch,
                                            psum, pcnt, 1.f/NN, NN);
  final_k<<<2, 256, 0, stream>>>(psum, pcnt, gattr, fc_w, fc_b, out, GG);
}

// Round 12
// 319.689 us; speedup vs baseline: 1.7420x; 1.1875x over previous
//
#include <hip/hip_runtime.h>

#define NN 50000
#define EE 500000
#define GG 512

typedef _Float16 f16x8 __attribute__((ext_vector_type(8)));
typedef _Float16 f16x2 __attribute__((ext_vector_type(2)));
typedef float f32x16 __attribute__((ext_vector_type(16)));

union F16x8U { f16x8 v8; f16x2 v2[4]; unsigned u[4]; };

__device__ __forceinline__ unsigned splat_h(float a){
  return __builtin_bit_cast(unsigned, __builtin_amdgcn_cvt_pkrtz(a, a));
}

// async global->LDS, 16B per lane; LDS dest = wave-uniform base + lane*16
__device__ __forceinline__ void gload16(const _Float16* g, _Float16* l){
  __builtin_amdgcn_global_load_lds(
      (const __attribute__((address_space(1))) unsigned int*)g,
      (__attribute__((address_space(3))) unsigned int*)l, 16, 0, 0);
}

// ---------------------------------------------------------------------------
// Prep: f16 tables in COALESCED lane-major layout.
//  BtL[t][lane][8]: lane=(hi<<5)|col reads ki = 16t + 8hi + j for column col.
// ---------------------------------------------------------------------------
#define NL1 (20*512)
#define NL2 (72*512)
__launch_bounds__(256)
__global__ void prep_k(const float* __restrict__ x,
                       const float* __restrict__ w2a, const float* __restrict__ b2a,
                       const float* __restrict__ w2b, const float* __restrict__ b2b,
                       _Float16* __restrict__ xh, _Float16* __restrict__ BtL1,
                       _Float16* __restrict__ BtL2)
{
  int idx = blockIdx.x*256 + threadIdx.x;
  if (idx < NL1){
    int t = idx >> 9, r = idx & 511;
    int lane = r >> 3, j = r & 7;
    int col = lane & 31, hi = lane >> 5;
    int ki = 16*t + 8*hi + j;
    int k = ki >> 3, i = ki & 7;
    float v = 0.f;
    if (i < 6){
      if (k < 32)       v = w2a[k*192 + i*32 + col];
      else if (k == 32) v = b2a[i*32 + col];
    }
    BtL1[idx] = (_Float16)v;
  } else if (idx < NL1 + NL2){
    int q = idx - NL1;
    int t = q >> 9, r = q & 511;
    int lane = r >> 3, j = r & 7;
    int col = lane & 31, hi = lane >> 5;
    int ki = 16*t + 8*hi + j;
    int k = ki >> 5, i = ki & 31;
    float v = 0.f;
    if (k < 32)       v = w2b[k*1024 + i*32 + col];
    else if (k == 32) v = b2b[i*32 + col];
    BtL2[q] = (_Float16)v;
  } else {
    int j = idx - (NL1 + NL2);
    if (j < NN*8){
      int n = j >> 3, i = j & 7;
      xh[j] = (_Float16)((i < 6) ? x[n*6 + i] : 0.f);
    }
  }
}

// ---------------------------------------------------------------------------
// Counting sort by dst: histogram -> 2-level exclusive scan -> scatter.
// ---------------------------------------------------------------------------
__launch_bounds__(256)
__global__ void hist_k(const int* __restrict__ ei, int* __restrict__ hist)
{
  int e = blockIdx.x*256 + threadIdx.x;
  if (e < EE) atomicAdd(&hist[ei[EE + e]], 1);
}

__launch_bounds__(256)
__global__ void scan1_k(const int* __restrict__ hist, int* __restrict__ part,
                        int* __restrict__ blk)
{
  __shared__ int s[256];
  int t = threadIdx.x, b = blockIdx.x, i = b*256 + t;
  int v = (i < NN) ? hist[i] : 0;
  s[t] = v; __syncthreads();
  #pragma unroll
  for (int off = 1; off < 256; off <<= 1){
    int u = (t >= off) ? s[t-off] : 0;
    __syncthreads();
    s[t] += u;
    __syncthreads();
  }
  if (i < NN) part[i] = s[t] - v;          // exclusive within block
  if (t == 255) blk[b] = s[255];           // block total
}

__launch_bounds__(256)
__global__ void scan2_k(int* __restrict__ blk, int nblk)
{
  __shared__ int s[256];
  int t = threadIdx.x;
  int v = (t < nblk) ? blk[t] : 0;
  s[t] = v; __syncthreads();
  #pragma unroll
  for (int off = 1; off < 256; off <<= 1){
    int u = (t >= off) ? s[t-off] : 0;
    __syncthreads();
    s[t] += u;
    __syncthreads();
  }
  if (t < nblk) blk[t] = s[t] - v;         // exclusive across blocks
}

__launch_bounds__(256)
__global__ void rowptr_k(const int* __restrict__ part, const int* __restrict__ blk,
                         int* __restrict__ rowptr)
{
  int n = blockIdx.x*256 + threadIdx.x;
  if (n < NN) rowptr[n] = part[n] + blk[n >> 8];
}

__launch_bounds__(256)
__global__ void scatter_k(const int* __restrict__ ei, const float* __restrict__ ea,
                          const int* __restrict__ rowptr, int* __restrict__ cursor,
                          int* __restrict__ esrc, int* __restrict__ edst,
                          float* __restrict__ eap)
{
  int e = blockIdx.x*256 + threadIdx.x;
  if (e < EE){
    int d = ei[EE + e];
    int slot = rowptr[d] + atomicAdd(&cursor[d], 1);
    esrc[slot] = ei[e];
    edst[slot] = d;
    #pragma unroll
    for (int q = 0; q < 5; ++q) eap[(long)slot*5 + q] = ea[(long)e*5 + q];
  }
}

// ---------------------------------------------------------------------------
// NNConv messages on dst-sorted edges: block = 128 edges (4 waves x 32),
// mfma 32x32x16 f16.  B staged in LDS via global_load_lds; in-block
// segmented reduction; ONE store/atomic per (dst,col).
// D: col = lane&31, row = (reg&3) + 8*(reg>>2) + 4*(lane>>5).
// ---------------------------------------------------------------------------
template<int CONV>
__launch_bounds__(256, 4)
__global__ void conv_msg_k(const _Float16* __restrict__ xh,
                           const int* __restrict__ esrc,
                           const int* __restrict__ edst,
                           const float* __restrict__ eap,
                           const float* __restrict__ w1,
                           const float* __restrict__ b1,
                           const _Float16* __restrict__ Btg,
                           const int* __restrict__ rowptr,
                           const int* __restrict__ deg,
                           float* __restrict__ agg)
{
  constexpr int BTB_F16 = (CONV == 1) ? 10240 : 8192;   // 20KB / 2x8KB
  __shared__ unsigned hs2[128][37];       // h' splats; reused as msg[128][37] floats
  __shared__ _Float16 btb[BTB_F16];
  __shared__ int segrow[130];
  __shared__ int segcnt[2];

  const int tid  = threadIdx.x;
  const int lane = tid & 63;
  const int wave = tid >> 6;
  const int e0   = blockIdx.x * 128;
  const int nvalid = (EE - e0 < 128) ? (EE - e0) : 128;

  // issue stage of first chunk (conv1: whole 20-slice table) before h' phase
  if (CONV == 1){
    #pragma unroll
    for (int i = 0; i < 5; ++i)
      gload16(Btg + (wave + 4*i)*512 + lane*8, btb + (wave + 4*i)*512);
  } else {
    gload16(Btg + wave*512 + lane*8,       btb + wave*512);
    gload16(Btg + (wave + 4)*512 + lane*8, btb + (wave + 4)*512);
  }

  // cooperative h' = relu(eap@w1 + b1), stored as splatted half2
  {
    int e  = tid >> 1;                    // 0..127
    int kb = (tid & 1) * 16;
    int eg = e0 + e;
    bool valid = eg < EE;
    float eav[5];
    #pragma unroll
    for (int q = 0; q < 5; ++q) eav[q] = valid ? eap[(long)eg*5 + q] : 0.f;
    #pragma unroll
    for (int k = kb; k < kb + 16; ++k){
      float a = b1[k];
      #pragma unroll
      for (int q = 0; q < 5; ++q) a += eav[q] * w1[q*32 + k];
      hs2[e][k] = splat_h(fmaxf(a, 0.f));
    }
    if (kb == 16){
      hs2[e][32] = splat_h(1.f);          // bias row (h' = 1)
      hs2[e][33] = 0u; hs2[e][34] = 0u; hs2[e][35] = 0u;
    }
  }
  __syncthreads();                        // hs2 ready AND first stage drained

  const int col = lane & 31;              // A-row (edge) AND B-col (output)
  const int hi  = lane >> 5;
  const int el  = wave*32 + col;          // block-local edge for A
  const int emy = e0 + el;
  const int src = (emy < EE) ? esrc[emy] : 0;

  // x fragments (f16 pairs), register-resident
  F16x8U xa, xb;
  if (CONV == 1){
    xa.v8 = *(const f16x8*)(xh + (long)src*8);
    xb.v8 = xa.v8;
  } else {
    xa.v8 = *(const f16x8*)(xh + (long)src*32 + 8*hi);
    xb.v8 = *(const f16x8*)(xh + (long)src*32 + 16 + 8*hi);
  }

  // h' splats, register-resident (static indexing under full unroll)
  unsigned h2[(CONV == 1) ? 18 : 34];
  if (CONV == 1){
    #pragma unroll
    for (int t = 0; t < 18; ++t) h2[t] = hs2[el][2*t + hi];
  } else {
    #pragma unroll
    for (int kk = 0; kk < 34; ++kk) h2[kk] = hs2[el][kk];
  }

  f32x16 acc;
  #pragma unroll
  for (int r = 0; r < 16; ++r) acc[r] = 0.f;

  if (CONV == 1){
    #pragma unroll
    for (int t = 0; t < 18; ++t){
      f16x8 bf = *(const f16x8*)&btb[t*512 + lane*8];
      f16x2 hv = __builtin_bit_cast(f16x2, h2[t]);
      F16x8U af;
      #pragma unroll
      for (int p = 0; p < 4; ++p) af.v2[p] = hv * xa.v2[p];
      acc = __builtin_amdgcn_mfma_f32_32x32x16_f16(af.v8, bf, acc, 0, 0, 0);
    }
    __syncthreads();                      // all reads of hs2/btb done
  } else {
    // 9 chunks of 8 slices (last uses 4), double-buffered
    #pragma unroll
    for (int c = 0; c < 9; ++c){
      if (c < 8){                         // stage chunk c+1 into buf (c+1)&1
        const _Float16* gs = Btg + (long)((c+1)*8 + wave)*512 + lane*8;
        _Float16* ls = btb + ((c+1)&1)*4096 + wave*512;
        gload16(gs, ls);
        gload16(gs + 4*512, ls + 4*512);
      }
      const int tmax = (c == 8) ? 4 : 8;
      #pragma unroll
      for (int tt = 0; tt < tmax; ++tt){
        const int t = c*8 + tt;
        f16x8 bf = *(const f16x8*)&btb[(c&1)*4096 + tt*512 + lane*8];
        f16x2 hv = __builtin_bit_cast(f16x2, h2[t >> 1]);
        const F16x8U& xs = (t & 1) ? xb : xa;
        F16x8U af;
        #pragma unroll
        for (int p = 0; p < 4; ++p) af.v2[p] = hv * xs.v2[p];
        acc = __builtin_amdgcn_mfma_f32_32x32x16_f16(af.v8, bf, acc, 0, 0, 0);
      }
      __syncthreads();                    // stage drained + buffer reads done
    }
  }

  float* msg = (float*)&hs2[0][0];        // reuse as [128][37]

  #pragma unroll
  for (int g = 0; g < 4; ++g){
    #pragma unroll
    for (int r = 0; r < 4; ++r){
      int row = wave*32 + r + 8*g + 4*hi;
      msg[row*37 + col] = acc[4*g + r];
    }
  }

  // segment detection over the 128 sorted edges (waves 0,1)
  bool st = false;
  if (tid < 128){
    int eg = e0 + tid;
    st = (tid < nvalid) && (tid == 0 || edst[eg] != edst[eg-1]);
  }
  unsigned long long m = __ballot(st);
  int rank = __popcll(m & ((1ull << lane) - 1ull));
  if (tid < 128 && lane == 0) segcnt[wave] = (int)__popcll(m);
  __syncthreads();
  if (st) segrow[rank + ((tid >= 64) ? segcnt[0] : 0)] = tid;
  if (tid == 128) segrow[segcnt[0] + segcnt[1]] = nvalid;   // sentinel
  __syncthreads();

  // segmented sum + one write per (dst, col)
  const int nseg = segcnt[0] + segcnt[1];
  const int c2 = tid & 31;
  for (int s = tid >> 5; s < nseg; s += 8){
    int r0 = segrow[s], r1 = segrow[s+1];
    float sum = 0.f;
    for (int r = r0; r < r1; ++r) sum += msg[r*37 + c2];
    int d  = edst[e0 + r0];
    int rp = rowptr[d];
    if (rp >= e0 && rp + deg[d] <= e0 + nvalid)
      agg[(long)d*32 + c2] = sum;         // node fully inside this block
    else
      atomicAdd(&agg[(long)d*32 + c2], sum);
  }
}

// ---------------------------------------------------------------------------
// h = agg/max(cnt,1) + x@root + bias (in place), accumulate BN stats.
// ---------------------------------------------------------------------------
template<int IN_C>
__launch_bounds__(256)
__global__ void node_update_k(const float* __restrict__ xin, const float* __restrict__ root,
                              const float* __restrict__ bias, const int* __restrict__ cnt,
                              float* __restrict__ buf, float* __restrict__ stats, int N)
{
  __shared__ float rs[IN_C*32];
  __shared__ float bs[32];
  __shared__ float redS[4][32], redQ[4][32];
  int tid = threadIdx.x;
  for (int i = tid; i < IN_C*32; i += 256) rs[i] = root[i];
  if (tid < 32) bs[tid] = bias[tid];
  __syncthreads();
  int o = tid & 31, slot = tid >> 5;
  float s = 0.f, q = 0.f;
  for (int n = blockIdx.x*8 + slot; n < N; n += gridDim.x*8){
    float c = fmaxf((float)cnt[n], 1.f);
    float v = buf[(long)n*32 + o] / c + bs[o];
    const float* xrow = &xin[(long)n*IN_C];
    #pragma unroll
    for (int i = 0; i < IN_C; ++i) v += xrow[i] * rs[i*32 + o];
    buf[(long)n*32 + o] = v;
    s += v; q += v*v;
  }
  s += __shfl_xor(s, 32); q += __shfl_xor(q, 32);
  int wv = tid >> 6;
  if ((tid & 63) < 32){ redS[wv][o] = s; redQ[wv][o] = q; }
  __syncthreads();
  if (tid < 32){
    float ts = 0.f, tq = 0.f;
    #pragma unroll
    for (int w = 0; w < 4; ++w){ ts += redS[w][tid]; tq += redQ[w][tid]; }
    atomicAdd(&stats[tid], ts); atomicAdd(&stats[32 + tid], tq);
  }
}

__launch_bounds__(256)
__global__ void bn_relu_k(float* __restrict__ buf, _Float16* __restrict__ bufh,
                          const float* __restrict__ stats,
                          const float* __restrict__ gg, const float* __restrict__ bb,
                          float invN, int total)
{
  int i = blockIdx.x*256 + threadIdx.x;
  if (i < total){
    int o = i & 31;
    float mu  = stats[o] * invN;
    float var = stats[32+o] * invN - mu*mu;
    float v = fmaxf((buf[i] - mu) * rsqrtf(var + 1e-5f) * gg[o] + bb[o], 0.f);
    buf[i]  = v;
    bufh[i] = (_Float16)v;
  }
}

// ---------------------------------------------------------------------------
// Graph mean-pool on SORTED batch: per-block segmented reduction.
// 512 nodes/block, 8 node-streams x 32 cols; register-accumulate per group,
// flush to LDS gsum on group change, one global atomic per (group,col)/block.
// Unsorted-robust via ls-range fallback to direct atomics.
// ---------------------------------------------------------------------------
__launch_bounds__(256)
__global__ void bn_pool_k(const float* __restrict__ buf, const float* __restrict__ stats,
                          const float* __restrict__ gg, const float* __restrict__ bb,
                          const int* __restrict__ batch, float* __restrict__ psum,
                          float* __restrict__ pcnt, float invN, int N)
{
  constexpr int NPB  = 512;
  constexpr int MAXG = 33;
  __shared__ float gsum[MAXG][33];        // [local group][col]; col 32 = count
  int tid = threadIdx.x;
  int n0  = blockIdx.x * NPB;
  for (int i = tid; i < MAXG*33; i += 256) (&gsum[0][0])[i] = 0.f;
  __syncthreads();

  int o = tid & 31, slot = tid >> 5;
  int gfirst = batch[n0];
  float mu  = stats[o] * invN;
  float var = stats[32+o] * invN - mu*mu;
  float sc  = rsqrtf(var + 1e-5f) * gg[o];
  float sh  = bb[o] - mu*sc;
  int nend  = (N - n0 < NPB) ? N : n0 + NPB;

  float acc = 0.f, cacc = 0.f;
  int curls = -1;
  for (int n = n0 + slot; n < nend; n += 8){
    int ls = batch[n] - gfirst;
    float v = fmaxf(buf[(long)n*32 + o]*sc + sh, 0.f);
    if (ls != curls){
      if (curls >= 0){
        if ((unsigned)curls < MAXG){
          if (acc  != 0.f) atomicAdd(&gsum[curls][o], acc);
          if (o == 0 && cacc != 0.f) atomicAdd(&gsum[curls][32], cacc);
        } else {
          if (acc  != 0.f) atomicAdd(&psum[(long)(gfirst+curls)*32 + o], acc);
          if (o == 0 && cacc != 0.f) atomicAdd(&pcnt[gfirst+curls], cacc);
        }
      }
      acc = 0.f; cacc = 0.f; curls = ls;
    }
    acc += v;
    if (o == 0) cacc += 1.f;
  }
  if (curls >= 0){
    if ((unsigned)curls < MAXG){
      if (acc  != 0.f) atomicAdd(&gsum[curls][o], acc);
      if (o == 0 && cacc != 0.f) atomicAdd(&gsum[curls][32], cacc);
    } else {
      if (acc  != 0.f) atomicAdd(&psum[(long)(gfirst+curls)*32 + o], acc);
      if (o == 0 && cacc != 0.f) atomicAdd(&pcnt[gfirst+curls], cacc);
    }
  }
  __syncthreads();

  for (int i = tid; i < MAXG*32; i += 256){
    int ls = i >> 5, c = i & 31;
    float v = gsum[ls][c];
    if (v != 0.f) atomicAdd(&psum[(long)(gfirst+ls)*32 + c], v);
  }
  if (tid < MAXG){
    float v = gsum[tid][32];
    if (v != 0.f) atomicAdd(&pcnt[gfirst + tid], v);
  }
}

__launch_bounds__(256)
__global__ void final_k(const float* __restrict__ psum, const float* __restrict__ pcnt,
                        const float* __restrict__ gattr, const float* __restrict__ fcw,
                        const float* __restrict__ fcb, float* __restrict__ out, int G)
{
  int g = blockIdx.x*256 + threadIdx.x;
  if (g < G){
    float c = fmaxf(pcnt[g], 1.f);
    float o0 = fcb[0], o1 = fcb[1], o2 = fcb[2];
    #pragma unroll
    for (int j = 0; j < 32; ++j){
      float p = psum[g*32+j] / c;
      o0 += p*fcw[j*3+0]; o1 += p*fcw[j*3+1]; o2 += p*fcw[j*3+2];
    }
    #pragma unroll
    for (int j = 0; j < 4; ++j){
      float a = gattr[g*4+j];
      o0 += a*fcw[(32+j)*3+0]; o1 += a*fcw[(32+j)*3+1]; o2 += a*fcw[(32+j)*3+2];
    }
    out[g*3+0] = o0; out[g*3+1] = o1; out[g*3+2] = o2;
  }
}

// ---------------------------------------------------------------------------
extern "C" void kernel_launch(void* const* d_in, const int* in_sizes, int n_in,
                              void* d_out, int out_size, void* d_ws, size_t ws_size,
                              hipStream_t stream)
{
  const float* x     = (const float*)d_in[0];
  const int*   ei    = (const int*)  d_in[1];
  const float* ea    = (const float*)d_in[2];
  const int*   batch = (const int*)  d_in[3];
  const float* gattr = (const float*)d_in[4];
  const float* e1_w1 = (const float*)d_in[5];
  const float* e1_b1 = (const float*)d_in[6];
  const float* e1_w2 = (const float*)d_in[7];
  const float* e1_b2 = (const float*)d_in[8];
  const float* root1 = (const float*)d_in[9];
  const float* bias1 = (const float*)d_in[10];
  const float* bn1_g = (const float*)d_in[11];
  const float* bn1_b = (const float*)d_in[12];
  const float* e2_w1 = (const float*)d_in[13];
  const float* e2_b1 = (const float*)d_in[14];
  const float* e2_w2 = (const float*)d_in[15];
  const float* e2_b2 = (const float*)d_in[16];
  const float* root2 = (const float*)d_in[17];
  const float* bias2 = (const float*)d_in[18];
  const float* bn2_g = (const float*)d_in[19];
  const float* bn2_b = (const float*)d_in[20];
  const float* fc_w  = (const float*)d_in[21];
  const float* fc_b  = (const float*)d_in[22];
  float* out = (float*)d_out;

  float* ws = (float*)d_ws;
  const long NM = (long)NN*32;
  const int NBLK = (NN + 255) / 256;      // 196 scan blocks

  // ---- zeroed region (contiguous) ----
  float* bufA   = ws;                     // [N][32] conv1 agg -> h1
  float* bufB   = bufA + NM;              // [N][32] conv2 agg -> h2
  float* stats  = bufB + NM;              // 128
  float* psum   = stats + 128;            // [G][32]
  float* pcnt   = psum + GG*32;           // [G]
  int*   hist   = (int*)(pcnt + GG);      // [N] in-degree
  int*   cursor = hist + NN;              // [N]
  long zero_elems = 2*NM + 128 + GG*32 + GG + 2L*NN;
  // ---- non-zeroed scratch ----
  int*   part   = cursor + NN;            // [N]  local exclusive scan
  int*   blk    = part + NN;              // [256] block sums
  int*   rowptr = blk + 256;              // [N] CSR row pointer
  int*   esrc   = rowptr + NN;            // [E] sorted src
  int*   edst   = esrc + EE;              // [E] sorted dst
  float* eap    = (float*)(edst + EE);    // [E][5] sorted edge attr
  _Float16* bufAh = (_Float16*)(eap + (long)EE*5);  // [N][32] f16 of h1
  _Float16* xh    = bufAh + NM;           // [N][8] f16 of x
  _Float16* BtL1  = xh + (long)NN*8;      // [20][64][8] coalesced
  _Float16* BtL2  = BtL1 + NL1;           // [72][64][8] coalesced

  (void)hipMemsetAsync(d_ws, 0, (size_t)zero_elems * 4, stream);

  const int PREP_ELEMS = NL1 + NL2 + NN*8;
  prep_k<<<(PREP_ELEMS + 255)/256, 256, 0, stream>>>(x, e1_w2, e1_b2, e2_w2, e2_b2,
                                                     xh, BtL1, BtL2);

  const int EGRID = (EE + 255)/256;       // 1954
  hist_k<<<EGRID, 256, 0, stream>>>(ei, hist);
  scan1_k<<<NBLK, 256, 0, stream>>>(hist, part, blk);
  scan2_k<<<1, 256, 0, stream>>>(blk, NBLK);
  rowptr_k<<<NBLK, 256, 0, stream>>>(part, blk, rowptr);
  scatter_k<<<EGRID, 256, 0, stream>>>(ei, ea, rowptr, cursor, esrc, edst, eap);

  const int EBLK = (EE + 127) / 128;      // 3907
  conv_msg_k<1><<<EBLK, 256, 0, stream>>>(xh, esrc, edst, eap, e1_w1, e1_b1, BtL1,
                                          rowptr, hist, bufA);
  node_update_k<6><<<256, 256, 0, stream>>>(x, root1, bias1, hist, bufA, stats, NN);
  bn_relu_k<<<(int)((NM + 255)/256), 256, 0, stream>>>(bufA, bufAh, stats, bn1_g, bn1_b,
                                                       1.f/NN, (int)NM);
  conv_msg_k<2><<<EBLK, 256, 0, stream>>>(bufAh, esrc, edst, eap, e2_w1, e2_b1, BtL2,
                                          rowptr, hist, bufB);
  node_update_k<32><<<256, 256, 0, stream>>>(bufA, root2, bias2, hist, bufB, stats + 64, NN);
  bn_pool_k<<<(NN + 511)/512, 256, 0, stream>>>(bufB, stats + 64, bn2_g, bn2_b, batch,
                                                psum, pcnt, 1.f/NN, NN);
  final_k<<<2, 256, 0, stream>>>(psum, pcnt, gattr, fc_w, fc_b, out, GG);
}